// Round 13
// baseline (1518.070 us; speedup 1.0000x reference)
//
#include <hip/hip_runtime.h>
#include <hip/hip_bf16.h>
#include <math.h>

typedef unsigned short u16;
typedef unsigned int u32;
typedef __attribute__((ext_vector_type(8))) __bf16 bf16x8;
typedef __attribute__((ext_vector_type(4))) float f32x4;
typedef __attribute__((ext_vector_type(16))) float f32x16;
typedef __attribute__((ext_vector_type(8))) u16 u16x8;
typedef __attribute__((ext_vector_type(4))) u16 u16x4;
typedef __attribute__((ext_vector_type(4))) u32 u32x4;

#define DEV static __device__ __forceinline__

DEV u16 f2bf(float x) {
  __bf16 b = (__bf16)x;
  return __builtin_bit_cast(u16, b);
}
DEV float bf2f(u16 u) {
  unsigned v = ((unsigned)u) << 16;
  return __builtin_bit_cast(float, v);
}

DEV void gl_lds16(const u16* g, u16* l) {
  __builtin_amdgcn_global_load_lds(
      (const __attribute__((address_space(1))) void*)g,
      (__attribute__((address_space(3))) void*)l, 16, 0, 0);
}

DEV float waveRedSum(float v) {
  v += __shfl_xor(v, 1);  v += __shfl_xor(v, 2);  v += __shfl_xor(v, 4);
  v += __shfl_xor(v, 8);  v += __shfl_xor(v, 16); v += __shfl_xor(v, 32);
  return v;
}

// --- attention helpers -------------------------------------------------------
DEV float exp2_fast(float x) {
  float r;
  asm("v_exp_f32 %0, %1" : "=v"(r) : "v"(x));
  return r;
}
DEV float vmax16(f32x16 v) {
  float a = fmaxf(v[0], v[1]), b = fmaxf(v[2], v[3]);
  float c = fmaxf(v[4], v[5]), d = fmaxf(v[6], v[7]);
  float e = fmaxf(v[8], v[9]), f = fmaxf(v[10], v[11]);
  float g = fmaxf(v[12], v[13]), h = fmaxf(v[14], v[15]);
  a = fmaxf(a, b); c = fmaxf(c, d); e = fmaxf(e, f); g = fmaxf(g, h);
  return fmaxf(fmaxf(a, c), fmaxf(e, g));
}
DEV float vsum16(f32x16 v) {
  float a = v[0] + v[1], b = v[2] + v[3], c = v[4] + v[5], d = v[6] + v[7];
  float e = v[8] + v[9], f = v[10] + v[11], g = v[12] + v[13], h = v[14] + v[15];
  a += b; c += d; e += f; g += h;
  return (a + c) + (e + g);
}
DEV f32x16 mfma32(bf16x8 a, bf16x8 b, f32x16 c) {
  return __builtin_amdgcn_mfma_f32_32x32x16_bf16(a, b, c, 0, 0, 0);
}
DEV f32x4 mfma16(bf16x8 a, bf16x8 b, f32x4 c) {
  return __builtin_amdgcn_mfma_f32_16x16x32_bf16(a, b, c, 0, 0, 0);
}
DEV u32 pack2(float lo, float hi2) {
  return ((u32)f2bf(hi2) << 16) | (u32)f2bf(lo);
}
// P^T -> PV B-fragment, DIRECT register order (vt s-cols are bit2<->3 swizzled;
// both-sides-same-permutation => no cross-lane repack needed).
DEV void pack_direct(const f32x16& s, bf16x8* out) {
  u32x4 f0 = {pack2(s[0], s[1]),   pack2(s[2], s[3]),
              pack2(s[4], s[5]),   pack2(s[6], s[7])};
  u32x4 f1 = {pack2(s[8], s[9]),   pack2(s[10], s[11]),
              pack2(s[12], s[13]), pack2(s[14], s[15])};
  out[0] = __builtin_bit_cast(bf16x8, f0);
  out[1] = __builtin_bit_cast(bf16x8, f1);
}

// ---------------------------------------------------------------- cvt f32->bf16
__global__ __launch_bounds__(256)
void cvt_f32_bf16(const float* __restrict__ in, u16* __restrict__ out, int n8) {
  int i = blockIdx.x * 256 + threadIdx.x;
  if (i >= n8) return;
  const float4 a = *(const float4*)(in + (size_t)i * 8);
  const float4 b = *(const float4*)(in + (size_t)i * 8 + 4);
  u16x8 o;
  o[0] = f2bf(a.x); o[1] = f2bf(a.y); o[2] = f2bf(a.z); o[3] = f2bf(a.w);
  o[4] = f2bf(b.x); o[5] = f2bf(b.y); o[6] = f2bf(b.z); o[7] = f2bf(b.w);
  *(u16x8*)(out + (size_t)i * 8) = o;
}

// ------------------------------------------------ pack Wq/Wk/Wv [H,D,DH] -> bf16 [3072][1024] (N,K)
__global__ __launch_bounds__(256)
void pack_wqkv(const float* __restrict__ Wq, const float* __restrict__ Wk,
               const float* __restrict__ Wv, u16* __restrict__ out) {
  __shared__ float tl[64][65];
  int bid = blockIdx.x;              // 3 * 16 * 16 = 768
  int which = bid / 256;
  int rem = bid % 256;
  int h = rem / 16, dt = rem % 16;
  const float* W = (which == 0) ? Wq : (which == 1) ? Wk : Wv;
  int t = threadIdx.x, tx = t & 63, ty = t >> 6;
  const float* src = W + (size_t)h * 65536 + (size_t)dt * 64 * 64;  // [d][e]
#pragma unroll
  for (int i = 0; i < 16; ++i) {
    int dr = ty * 16 + i;
    tl[dr][tx] = src[(size_t)dr * 64 + tx];
  }
  __syncthreads();
#pragma unroll
  for (int i = 0; i < 16; ++i) {
    int e = ty * 16 + i;
    out[(size_t)(which * 1024 + h * 64 + e) * 1024 + dt * 64 + tx] = f2bf(tl[tx][e]);
  }
}

// ------------------------------------------------ pack W [K][N] -> Wt bf16 [N][K]
__global__ __launch_bounds__(256)
void pack_wt(const float* __restrict__ W, u16* __restrict__ out, int K, int N) {
  __shared__ float tl[64][65];
  int ntiles = N >> 6;
  int kt = blockIdx.x / ntiles, nt = blockIdx.x % ntiles;
  int t = threadIdx.x, tx = t & 63, ty = t >> 6;
#pragma unroll
  for (int i = 0; i < 16; ++i) {
    int kr = ty * 16 + i;
    tl[kr][tx] = W[(size_t)(kt * 64 + kr) * N + nt * 64 + tx];
  }
  __syncthreads();
#pragma unroll
  for (int i = 0; i < 16; ++i) {
    int nr = ty * 16 + i;
    out[(size_t)(nt * 64 + nr) * K + kt * 64 + tx] = f2bf(tl[tx][nr]);
  }
}

// ================================================================ 256x256 GEMM, 2 blocks/CU
// C[M,N] = A[M,K] * Bt[N,K]^T.  BM=BN=256, BK=32, 512 thr = 8 waves (2x4),
// wave-tile 128x64.  2 LDS slots of 32KB = 64 KB -> 2 blocks/CU (the R9/R12
// deep-pipeline attempts lost to 1-block/CU occupancy; this keeps 2).
// Same single-barrier skeleton as gemm256 (proven bit-exact twice):
//   { vmcnt(0); s_barrier; STAGE(t+1) -> slot (t-1)&1; 12 ds_reads; 32 MFMA }
// Race safety: STAGE(t+1) writes the slot read at t-1; at barrier_t every
// wave's t-1 MFMAs ran => its ds_reads completed (lgkm wait precedes MFMA).
// Readiness: at the wait, outstanding = exactly STAGE(t)'s 4 loads (issued
// one iteration earlier) -> vmcnt(0) is counted, not a pipeline drain; the
// co-resident block covers the wait.
// Intensity: 128 FLOP/staged-byte (vs 85 at 128x256) -> operand supply
// 38 -> 25 B/cyc/CU at full MFMA rate; LDS-read 2260cyc <= MFMA 2480cyc.
// Per-acc-element k-order identical to gemm256 -> bit-identical results.
// LDS swizzle: 16B-chunk col ^= (row>>1)&3 on staging SOURCE (linear dest)
// and read addresses (proven 0-conflict).
// EPI: 2 = bf16+bias+GELU; 3 = QKV pack (q/k/vt).
template <int EPI>
__global__ __launch_bounds__(512, 4)
void gemmBig(const u16* __restrict__ A, const u16* __restrict__ Bt,
             void* __restrict__ Cout, const float* __restrict__ bias,
             int M, int N, int K,
             u16* __restrict__ qp_out, u16* __restrict__ kp_out,
             u16* __restrict__ vt_out) {
  constexpr int SLOT = 16384;   // u16: A 8192 (256x32) + B 8192 = 32 KB
  __shared__ __align__(16) u16 lds[2 * SLOT];   // 64 KB

  const int t = threadIdx.x;
  const int lane = t & 63, w = t >> 6;
  const int li = lane & 15, lg = lane >> 4;
  const int wm = w >> 2, wn = w & 3;

  const int tiles_n = N >> 8;
  const int nwg = gridDim.x;
  const int wgid = (blockIdx.x & 7) * (nwg >> 3) + (blockIdx.x >> 3);
  const int m0 = (wgid / tiles_n) << 8;
  const int n0 = (wgid % tiles_n) << 8;

  // staging: thread t covers (row t>>2, chunk t&3); +128-row partner load.
  const int srow = t >> 2;
  const int scol = (((t & 3) ^ ((t >> 3) & 3)) << 3);  // swizzled source col
  const u16* aS0 = A  + (size_t)(m0 + srow) * K + scol;
  const u16* aS1 = A  + (size_t)(m0 + 128 + srow) * K + scol;
  const u16* bS0 = Bt + (size_t)(n0 + srow) * K + scol;
  const u16* bS1 = Bt + (size_t)(n0 + 128 + srow) * K + scol;
  u16* dWave = &lds[w * 512];           // wave-uniform LDS dest base

  // ds_read offsets (u16 units), swizzle-matched; row stride 32 u16
  int aOff[8], bOff[4];
#pragma unroll
  for (int i = 0; i < 8; ++i) {
    int row = wm * 128 + i * 16 + li;
    aOff[i] = row * 32 + ((lg ^ ((row >> 1) & 3)) << 3);
  }
#pragma unroll
  for (int j = 0; j < 4; ++j) {
    int row = wn * 64 + j * 16 + li;
    bOff[j] = 8192 + row * 32 + ((lg ^ ((row >> 1) & 3)) << 3);
  }

  f32x4 acc[8][4] = {};
  const int NT = K >> 5;

#define STAGEBIG(TT, SL)                                             \
  {                                                                  \
    const int kk = (TT) << 5;                                        \
    u16* db = dWave + (SL) * SLOT;                                   \
    gl_lds16(aS0 + kk, db);                                          \
    gl_lds16(aS1 + kk, db + 4096);                                   \
    gl_lds16(bS0 + kk, db + 8192);                                   \
    gl_lds16(bS1 + kk, db + 8192 + 4096);                            \
  }

  STAGEBIG(0, 0);

  for (int tt = 0; tt < NT; ++tt) {
    asm volatile("s_waitcnt vmcnt(0)" ::: "memory");  // = STAGE(tt) complete
    __builtin_amdgcn_s_barrier();          // single barrier per K-step
    __builtin_amdgcn_sched_barrier(0);     // nothing moves across

    if (tt + 1 < NT) STAGEBIG(tt + 1, (tt + 1) & 1); // slot read at t-1 (safe)

    const u16* sb = &lds[(tt & 1) * SLOT];
    bf16x8 af[8], bfr[4];
#pragma unroll
    for (int i = 0; i < 8; ++i) af[i] = *(const bf16x8*)&sb[aOff[i]];
#pragma unroll
    for (int j = 0; j < 4; ++j) bfr[j] = *(const bf16x8*)&sb[bOff[j]];

    __builtin_amdgcn_s_setprio(1);
#pragma unroll
    for (int i = 0; i < 8; ++i)
#pragma unroll
      for (int j = 0; j < 4; ++j)
        acc[i][j] = mfma16(af[i], bfr[j], acc[i][j]);
    __builtin_amdgcn_s_setprio(0);
  }
#undef STAGEBIG

  if constexpr (EPI == 3) {
    const int which = n0 >> 10;                 // block-uniform: 0=q 1=k 2=v
    const int colb = (n0 & 1023) + wn * 64 + li;
#pragma unroll
    for (int i = 0; i < 8; ++i) {
      const int row0 = m0 + wm * 128 + i * 16 + lg * 4;
      const int bb = row0 >> 10;
      const int s0r = row0 & 1023;
#pragma unroll
      for (int j = 0; j < 4; ++j) {
        const int c = colb + j * 16;
        const int hh = c >> 6, e = c & 63;
        const size_t hb = ((size_t)(bb * 16 + hh)) << 16;   // bh * 1024*64
        if (which == 2) {
          u16x4 pk;
#pragma unroll
          for (int r = 0; r < 4; ++r) pk[r] = f2bf(acc[i][j][r]);
          const int s_sw = (s0r & ~12) | ((s0r & 4) << 1) | ((s0r & 8) >> 1);
          *(u16x4*)(vt_out + hb + ((size_t)e << 10) + s_sw) = pk;
        } else {
          u16* dst = (which == 0) ? qp_out : kp_out;
#pragma unroll
          for (int r = 0; r < 4; ++r)
            dst[hb + (size_t)(s0r + r) * 64 + e] = f2bf(acc[i][j][r]);
        }
      }
    }
    return;
  }

  const int colBase = n0 + wn * 64 + li;
#pragma unroll
  for (int i = 0; i < 8; ++i) {
#pragma unroll
    for (int j = 0; j < 4; ++j) {
      int col = colBase + j * 16;
      float bv = bias[col];
#pragma unroll
      for (int r = 0; r < 4; ++r) {
        int row = m0 + wm * 128 + i * 16 + lg * 4 + r;
        float v = acc[i][j][r] + bv;
        if (EPI == 2) v = 0.5f * v * (1.0f + erff(v * 0.70710678118654752f));
        ((u16*)Cout)[(size_t)row * N + col] = f2bf(v);
      }
    }
  }
}

// ================================================================ 128x256 GEMM (R9 structure)
// EPI: 1 = f32+bias; 2 = bf16+bias+GELU; 4 = bf16+bias.
template <int EPI>
__global__ __launch_bounds__(512, 4)
void gemm256(const u16* __restrict__ A, const u16* __restrict__ Bt,
             void* __restrict__ Cout, const float* __restrict__ bias,
             int M, int N, int K) {
  constexpr int BM = 128, BN = 256;
  constexpr int SLOT = (BM + BN) * 32;  // u16 per slot (12288)
  __shared__ __align__(16) u16 lds[3 * SLOT];

  const int t = threadIdx.x;
  const int lane = t & 63, w = t >> 6;
  const int li = lane & 15, lg = lane >> 4;
  const int wm = w >> 2, wn = w & 3;

  const int tiles_n = N >> 8;
  const int nwg = gridDim.x;
  const int wgid = (blockIdx.x & 7) * (nwg >> 3) + (blockIdx.x >> 3);
  const int m0 = (wgid / tiles_n) * BM;
  const int n0 = (wgid % tiles_n) << 8;

  const int srow = t >> 2;
  const int scol = (((t & 3) ^ ((t >> 3) & 3)) << 3);  // swizzled source col
  const u16* aS0 = A  + (size_t)(m0 + srow) * K + scol;
  const u16* bS0 = Bt + (size_t)(n0 + srow) * K + scol;
  const u16* bS1 = Bt + (size_t)(n0 + 128 + srow) * K + scol;
  u16* dWave = &lds[w * 512];           // wave-uniform LDS dest base

  int aOff[4], bOff[4];
#pragma unroll
  for (int i = 0; i < 4; ++i) {
    int row = wm * 64 + i * 16 + li;
    aOff[i] = row * 32 + ((lg ^ ((row >> 1) & 3)) << 3);
  }
#pragma unroll
  for (int j = 0; j < 4; ++j) {
    int row = wn * 64 + j * 16 + li;
    bOff[j] = BM * 32 + row * 32 + ((lg ^ ((row >> 1) & 3)) << 3);
  }

  f32x4 acc[4][4] = {};
  const int NT = K >> 5;

#define STAGE256(TT, SL)                                             \
  {                                                                  \
    const int kk = (TT) << 5;                                        \
    u16* db = dWave + (SL) * SLOT;                                   \
    gl_lds16(aS0 + kk, db);                                          \
    gl_lds16(bS0 + kk, db + BM * 32);                                \
    gl_lds16(bS1 + kk, db + BM * 32 + 4096);                         \
  }

  STAGE256(0, 0);
  STAGE256(1, 1);

  int so = 0;
  for (int tt = 0; tt < NT; ++tt) {
    if (tt + 1 < NT) asm volatile("s_waitcnt vmcnt(3)" ::: "memory");
    else             asm volatile("s_waitcnt vmcnt(0)" ::: "memory");
    __builtin_amdgcn_s_barrier();          // single barrier per K-step
    __builtin_amdgcn_sched_barrier(0);     // nothing moves across

    int s2 = so + 2; if (s2 >= 3) s2 -= 3;
    if (tt + 2 < NT) STAGE256(tt + 2, s2); // writes slot read at t-1 (safe)

    const u16* sb = &lds[so * SLOT];
    bf16x8 af[4], bfr[4];
#pragma unroll
    for (int i = 0; i < 4; ++i) af[i] = *(const bf16x8*)&sb[aOff[i]];
#pragma unroll
    for (int j = 0; j < 4; ++j) bfr[j] = *(const bf16x8*)&sb[bOff[j]];

    __builtin_amdgcn_s_setprio(1);
#pragma unroll
    for (int i = 0; i < 4; ++i)
#pragma unroll
      for (int j = 0; j < 4; ++j)
        acc[i][j] = mfma16(af[i], bfr[j], acc[i][j]);
    __builtin_amdgcn_s_setprio(0);

    so = (so + 1 == 3) ? 0 : so + 1;
  }
#undef STAGE256

  const int colBase = n0 + wn * 64 + li;
#pragma unroll
  for (int i = 0; i < 4; ++i) {
#pragma unroll
    for (int j = 0; j < 4; ++j) {
      int col = colBase + j * 16;
      float bv = bias[col];
#pragma unroll
      for (int r = 0; r < 4; ++r) {
        int row = m0 + wm * 64 + i * 16 + lg * 4 + r;
        float v = acc[i][j][r] + bv;
        if (EPI == 2) v = 0.5f * v * (1.0f + erff(v * 0.70710678118654752f));
        if (EPI == 1) ((float*)Cout)[(size_t)row * N + col] = v;
        else          ((u16*)Cout)[(size_t)row * N + col] = f2bf(v);
      }
    }
  }
}

// ------------------------------------------------ flash attention, 32x32 swapped-QK^T
// qp/kp: [BH][S][64] bf16; vt: [BH][64][S] bf16 (s-cols bit2<->3 swizzled)
// K/V staged in LDS, double-buffered, slot-major [8 d-slots][64 rows]x16B.
__global__ __launch_bounds__(256, 2)
void attn32(const u16* __restrict__ qp, const u16* __restrict__ kp,
            const u16* __restrict__ vt, u16* __restrict__ ctx) {
  __shared__ __align__(16) u16 lds[2][2][4096];   // [buf][K=0/V=1][8KB]
  const int t = threadIdx.x, l = t & 63, w = t >> 6;
  const int l31 = l & 31, hi = l >> 5;
  const int bid = blockIdx.x;
  const int idx = bid >> 3;                 // 0..127
  const int bh = (bid & 7) * 16 + (idx >> 3);
  const int qt = idx & 7;
  const int b = bh >> 4, h = bh & 15;
  const int qg = qt * 128 + w * 32;
  const size_t base = (size_t)bh << 16;
  const float SC = 0.18033688011112042f;    // 0.125 * log2(e)

  const u16* qrow = qp + base + (size_t)(qg + l31) * 64 + 8 * hi;
  bf16x8 qb[4];
#pragma unroll
  for (int f = 0; f < 4; ++f) qb[f] = *(const bf16x8*)(qrow + f * 16);

  const u16* kbh = kp + base;
  const u16* vbh = vt + base;
  const int sl0 = w, sl1 = 4 + w;

#define STAGE_KV(KB, BUF)                                                        \
  {                                                                              \
    u16* KT = &lds[BUF][0][0];                                                   \
    u16* VT = &lds[BUF][1][0];                                                   \
    const u16* ks = kbh + (size_t)(KB) * 4096;                                   \
    const u16* vs = vbh + (KB) * 64;                                             \
    gl_lds16(ks + (size_t)l * 64 + sl0 * 8,   KT + sl0 * 512);                   \
    gl_lds16(ks + (size_t)l * 64 + sl1 * 8,   KT + sl1 * 512);                   \
    gl_lds16(vs + (size_t)l * 1024 + sl0 * 8, VT + sl0 * 512);                   \
    gl_lds16(vs + (size_t)l * 1024 + sl1 * 8, VT + sl1 * 512);                   \
  }

  f32x16 o0 = {}, o1 = {};
  float m_run = -1e30f, l_run = 0.0f;

  STAGE_KV(0, 0);
  __syncthreads();

  int buf = 0;
  for (int kb = 0; kb < 16; ++kb) {
    if (kb < 15) STAGE_KV(kb + 1, buf ^ 1);

    const u16* KT = &lds[buf][0][0];
    const u16* VT = &lds[buf][1][0];

    bf16x8 ka[8];
#pragma unroll
    for (int f = 0; f < 4; ++f) {
      const int s = (2 * f + hi) * 512 + l31 * 8;
      ka[f]     = *(const bf16x8*)&KT[s];
      ka[4 + f] = *(const bf16x8*)&KT[s + 256];
    }

    __builtin_amdgcn_s_setprio(1);
    f32x16 s0 = {}, s1 = {};
#pragma unroll
    for (int f = 0; f < 4; ++f) s0 = mfma32(ka[f], qb[f], s0);
#pragma unroll
    for (int f = 0; f < 4; ++f) s1 = mfma32(ka[4 + f], qb[f], s1);
    __builtin_amdgcn_s_setprio(0);

    bf16x8 va[8];
#pragma unroll
    for (int c = 0; c < 4; ++c) {
      const int s = (2 * c + hi) * 512 + l31 * 8;
      va[c]     = *(const bf16x8*)&VT[s];
      va[4 + c] = *(const bf16x8*)&VT[s + 256];
    }

    s0 *= SC; s1 *= SC;

    float mx = fmaxf(vmax16(s0), vmax16(s1));
    mx = fmaxf(mx, __shfl_xor(mx, 32));

    float mn = fmaxf(m_run, mx);
    float al = exp2_fast(m_run - mn);
    m_run = mn;
    l_run *= al; o0 *= al; o1 *= al;

#pragma unroll
    for (int i = 0; i < 16; ++i) s0[i] = exp2_fast(s0[i] - m_run);
#pragma unroll
    for (int i = 0; i < 16; ++i) s1[i] = exp2_fast(s1[i] - m_run);

    float sm = vsum16(s0) + vsum16(s1);
    sm += __shfl_xor(sm, 32);
    l_run += sm;

    bf16x8 pb[4];
    pack_direct(s0, &pb[0]);
    pack_direct(s1, &pb[2]);

    __builtin_amdgcn_s_setprio(1);
    o0 = mfma32(va[0], pb[0], o0);
    o0 = mfma32(va[1], pb[1], o0);
    o0 = mfma32(va[2], pb[2], o0);
    o0 = mfma32(va[3], pb[3], o0);
    o1 = mfma32(va[4], pb[0], o1);
    o1 = mfma32(va[5], pb[1], o1);
    o1 = mfma32(va[6], pb[2], o1);
    o1 = mfma32(va[7], pb[3], o1);
    __builtin_amdgcn_s_setprio(0);

    __syncthreads();
    buf ^= 1;
  }
#undef STAGE_KV

  float inv = 1.0f / l_run;
  o0 *= inv; o1 *= inv;
  u16* crow = ctx + (size_t)(b * 1024 + qg + l31) * 1024 + h * 64 + 4 * hi;
#pragma unroll
  for (int g = 0; g < 4; ++g) {
    u16x4 p0, p1;
#pragma unroll
    for (int j = 0; j < 4; ++j) { p0[j] = f2bf(o0[g * 4 + j]); p1[j] = f2bf(o1[g * 4 + j]); }
    *(u16x4*)(crow + g * 8) = p0;
    *(u16x4*)(crow + 32 + g * 8) = p1;
  }
}

// ------------------------------------------------ LayerNorm (residual fused)
// MODE 0: in1 f32 (x), in2 bf16 (attn) -> out bf16   (h = LN(x+attn))
// MODE 1: in1 bf16 (h), in2 bf16 (ff2) -> out f32    (out = LN(h+ff2))
template <int MODE>
__global__ __launch_bounds__(256)
void ln_kernel(const void* __restrict__ in1v, const u16* __restrict__ in2,
               const float* __restrict__ g, const float* __restrict__ bt,
               void* __restrict__ outv) {
  __shared__ float red[4];
  const int row = blockIdx.x;
  const int t = threadIdx.x;
  const int c = t * 4;
  const size_t base = (size_t)row * 1024 + c;

  float a0, a1, a2, a3;
  {
    u16x4 yb = *(const u16x4*)(in2 + base);
    float y0 = bf2f(yb[0]), y1 = bf2f(yb[1]), y2 = bf2f(yb[2]), y3 = bf2f(yb[3]);
    if (MODE == 0) {
      const float4 x = *(const float4*)((const float*)in1v + base);
      a0 = x.x + y0; a1 = x.y + y1; a2 = x.z + y2; a3 = x.w + y3;
    } else {
      u16x4 xb = *(const u16x4*)((const u16*)in1v + base);
      a0 = bf2f(xb[0]) + y0; a1 = bf2f(xb[1]) + y1;
      a2 = bf2f(xb[2]) + y2; a3 = bf2f(xb[3]) + y3;
    }
  }
  float sum = waveRedSum(a0 + a1 + a2 + a3);
  if ((t & 63) == 0) red[t >> 6] = sum;
  __syncthreads();
  float mean = (red[0] + red[1] + red[2] + red[3]) * (1.0f / 1024.0f);
  __syncthreads();
  float d0 = a0 - mean, d1 = a1 - mean, d2 = a2 - mean, d3 = a3 - mean;
  float sq = waveRedSum(d0 * d0 + d1 * d1 + d2 * d2 + d3 * d3);
  if ((t & 63) == 0) red[t >> 6] = sq;
  __syncthreads();
  float var = (red[0] + red[1] + red[2] + red[3]) * (1.0f / 1023.0f);
  float inv = rsqrtf(var + 1e-5f);
  const float4 gv = *(const float4*)(g + c);
  const float4 bv = *(const float4*)(bt + c);
  float o0 = d0 * inv * gv.x + bv.x;
  float o1 = d1 * inv * gv.y + bv.y;
  float o2 = d2 * inv * gv.z + bv.z;
  float o3 = d3 * inv * gv.w + bv.w;
  if (MODE == 0) {
    u16x4 ob; ob[0] = f2bf(o0); ob[1] = f2bf(o1); ob[2] = f2bf(o2); ob[3] = f2bf(o3);
    *(u16x4*)((u16*)outv + base) = ob;
  } else {
    float4 of; of.x = o0; of.y = o1; of.z = o2; of.w = o3;
    *(float4*)((float*)outv + base) = of;
  }
}

// ================================================================ launcher
extern "C" void kernel_launch(void* const* d_in, const int* in_sizes, int n_in,
                              void* d_out, int out_size, void* d_ws, size_t ws_size,
                              hipStream_t stream) {
  const float* x  = (const float*)d_in[0];
  const float* Wq = (const float*)d_in[1];
  const float* Wk = (const float*)d_in[2];
  const float* Wv = (const float*)d_in[3];
  const float* Wo = (const float*)d_in[4];
  const float* bo = (const float*)d_in[5];
  const float* g1 = (const float*)d_in[6];
  const float* b1 = (const float*)d_in[7];
  const float* W1 = (const float*)d_in[8];
  const float* c1 = (const float*)d_in[9];
  const float* W2 = (const float*)d_in[10];
  const float* c2 = (const float*)d_in[11];
  const float* g2 = (const float*)d_in[12];
  const float* b2 = (const float*)d_in[13];
  float* out = (float*)d_out;

  // workspace layout (bytes)
  char* ws = (char*)d_ws;
  u16* xb     = (u16*)(ws + 0);           // 16,777,216  (reused as h_b later)
  u16* wqkv_b = (u16*)(ws + 16777216);    //  6,291,456
  u16* wo_b   = (u16*)(ws + 23068672);    //  2,097,152
  u16* w1_b   = (u16*)(ws + 25165824);    //  8,388,608
  u16* w2_b   = (u16*)(ws + 33554432);    //  8,388,608
  char* R1 = ws + 41943040;               // 100,663,296 region, aliased over time
  u16*  qpb  = (u16*)(R1);                 // 16,777,216  live: qkv->attn
  u16*  kpb  = (u16*)(R1 + 16777216);      // 16,777,216  live: qkv->attn
  u16*  vtb  = (u16*)(R1 + 33554432);      // 16,777,216  live: qkv->attn
  u16*  ctx  = (u16*)(R1 + 50331648);      // 16,777,216  live: attn->Wo
  u16*  attn = (u16*)(R1 + 67108864);      // 16,777,216  live: Wo->ln1 (bf16)
  u16*  ff1  = (u16*)(R1);                 // 67,108,864  live: FFN1->FFN2 (aliases qp/kp/vt/ctx)
  u16*  ff2  = (u16*)(R1 + 83886080);      // 16,777,216  live: FFN2->ln2 (bf16)
  u16*  h_b  = xb;                         // live: ln1->end (aliases xb)

  cvt_f32_bf16<<<4096, 256, 0, stream>>>(x, xb, 1048576);
  pack_wqkv<<<768, 256, 0, stream>>>(Wq, Wk, Wv, wqkv_b);
  pack_wt<<<256, 256, 0, stream>>>(Wo, wo_b, 1024, 1024);
  pack_wt<<<1024, 256, 0, stream>>>(W1, w1_b, 1024, 4096);
  pack_wt<<<1024, 256, 0, stream>>>(W2, w2_b, 4096, 1024);

  // QKV: [8192,3072,1024] with q/k/vt packing epilogue (256^2, 2 blocks/CU)
  gemmBig<3><<<384, 512, 0, stream>>>(xb, wqkv_b, nullptr, nullptr,
                                      8192, 3072, 1024, qpb, kpb, vtb);
  attn32<<<1024, 256, 0, stream>>>(qpb, kpb, vtb, ctx);
  // Wo: [8192,1024,1024] -> bf16 + bias
  gemm256<4><<<256, 512, 0, stream>>>(ctx, wo_b, attn, bo, 8192, 1024, 1024);
  ln_kernel<0><<<8192, 256, 0, stream>>>(x, attn, g1, b1, h_b);
  // FFN1: [8192,4096,1024] -> bf16 + bias + GELU (256^2, 2 blocks/CU)
  gemmBig<2><<<512, 512, 0, stream>>>(h_b, w1_b, ff1, c1, 8192, 4096, 1024,
                                      nullptr, nullptr, nullptr);
  // FFN2: [8192,1024,4096] -> bf16 + bias
  gemm256<4><<<256, 512, 0, stream>>>(ff1, w2_b, ff2, c2, 8192, 1024, 4096);
  ln_kernel<1><<<8192, 256, 0, stream>>>(h_b, ff2, g2, b2, out);
}

// Round 14
// 349.551 us; speedup vs baseline: 4.3429x; 4.3429x over previous
//
#include <hip/hip_runtime.h>
#include <hip/hip_bf16.h>
#include <math.h>

typedef unsigned short u16;
typedef unsigned int u32;
typedef __attribute__((ext_vector_type(8))) __bf16 bf16x8;
typedef __attribute__((ext_vector_type(4))) float f32x4;
typedef __attribute__((ext_vector_type(16))) float f32x16;
typedef __attribute__((ext_vector_type(8))) u16 u16x8;
typedef __attribute__((ext_vector_type(4))) u16 u16x4;
typedef __attribute__((ext_vector_type(4))) u32 u32x4;

#define DEV static __device__ __forceinline__

DEV u16 f2bf(float x) {
  __bf16 b = (__bf16)x;
  return __builtin_bit_cast(u16, b);
}
DEV float bf2f(u16 u) {
  unsigned v = ((unsigned)u) << 16;
  return __builtin_bit_cast(float, v);
}

DEV void gl_lds16(const u16* g, u16* l) {
  __builtin_amdgcn_global_load_lds(
      (const __attribute__((address_space(1))) void*)g,
      (__attribute__((address_space(3))) void*)l, 16, 0, 0);
}

DEV float waveRedSum(float v) {
  v += __shfl_xor(v, 1);  v += __shfl_xor(v, 2);  v += __shfl_xor(v, 4);
  v += __shfl_xor(v, 8);  v += __shfl_xor(v, 16); v += __shfl_xor(v, 32);
  return v;
}

// --- attention helpers -------------------------------------------------------
DEV float exp2_fast(float x) {
  float r;
  asm("v_exp_f32 %0, %1" : "=v"(r) : "v"(x));
  return r;
}
DEV float vmax16(f32x16 v) {
  float a = fmaxf(v[0], v[1]), b = fmaxf(v[2], v[3]);
  float c = fmaxf(v[4], v[5]), d = fmaxf(v[6], v[7]);
  float e = fmaxf(v[8], v[9]), f = fmaxf(v[10], v[11]);
  float g = fmaxf(v[12], v[13]), h = fmaxf(v[14], v[15]);
  a = fmaxf(a, b); c = fmaxf(c, d); e = fmaxf(e, f); g = fmaxf(g, h);
  return fmaxf(fmaxf(a, c), fmaxf(e, g));
}
DEV float vsum16(f32x16 v) {
  float a = v[0] + v[1], b = v[2] + v[3], c = v[4] + v[5], d = v[6] + v[7];
  float e = v[8] + v[9], f = v[10] + v[11], g = v[12] + v[13], h = v[14] + v[15];
  a += b; c += d; e += f; g += h;
  return (a + c) + (e + g);
}
DEV f32x16 mfma32(bf16x8 a, bf16x8 b, f32x16 c) {
  return __builtin_amdgcn_mfma_f32_32x32x16_bf16(a, b, c, 0, 0, 0);
}
DEV f32x4 mfma16(bf16x8 a, bf16x8 b, f32x4 c) {
  return __builtin_amdgcn_mfma_f32_16x16x32_bf16(a, b, c, 0, 0, 0);
}
DEV u32 pack2(float lo, float hi2) {
  return ((u32)f2bf(hi2) << 16) | (u32)f2bf(lo);
}
// P^T -> PV B-fragment, DIRECT register order (vt s-cols are bit2<->3 swizzled;
// both-sides-same-permutation => no cross-lane repack needed).
DEV void pack_direct(const f32x16& s, bf16x8* out) {
  u32x4 f0 = {pack2(s[0], s[1]),   pack2(s[2], s[3]),
              pack2(s[4], s[5]),   pack2(s[6], s[7])};
  u32x4 f1 = {pack2(s[8], s[9]),   pack2(s[10], s[11]),
              pack2(s[12], s[13]), pack2(s[14], s[15])};
  out[0] = __builtin_bit_cast(bf16x8, f0);
  out[1] = __builtin_bit_cast(bf16x8, f1);
}

// ---------------------------------------------------------------- cvt f32->bf16
__global__ __launch_bounds__(256)
void cvt_f32_bf16(const float* __restrict__ in, u16* __restrict__ out, int n8) {
  int i = blockIdx.x * 256 + threadIdx.x;
  if (i >= n8) return;
  const float4 a = *(const float4*)(in + (size_t)i * 8);
  const float4 b = *(const float4*)(in + (size_t)i * 8 + 4);
  u16x8 o;
  o[0] = f2bf(a.x); o[1] = f2bf(a.y); o[2] = f2bf(a.z); o[3] = f2bf(a.w);
  o[4] = f2bf(b.x); o[5] = f2bf(b.y); o[6] = f2bf(b.z); o[7] = f2bf(b.w);
  *(u16x8*)(out + (size_t)i * 8) = o;
}

// ------------------------------------------------ pack Wq/Wk/Wv [H,D,DH] -> bf16 [3072][1024] (N,K)
__global__ __launch_bounds__(256)
void pack_wqkv(const float* __restrict__ Wq, const float* __restrict__ Wk,
               const float* __restrict__ Wv, u16* __restrict__ out) {
  __shared__ float tl[64][65];
  int bid = blockIdx.x;              // 3 * 16 * 16 = 768
  int which = bid / 256;
  int rem = bid % 256;
  int h = rem / 16, dt = rem % 16;
  const float* W = (which == 0) ? Wq : (which == 1) ? Wk : Wv;
  int t = threadIdx.x, tx = t & 63, ty = t >> 6;
  const float* src = W + (size_t)h * 65536 + (size_t)dt * 64 * 64;  // [d][e]
#pragma unroll
  for (int i = 0; i < 16; ++i) {
    int dr = ty * 16 + i;
    tl[dr][tx] = src[(size_t)dr * 64 + tx];
  }
  __syncthreads();
#pragma unroll
  for (int i = 0; i < 16; ++i) {
    int e = ty * 16 + i;
    out[(size_t)(which * 1024 + h * 64 + e) * 1024 + dt * 64 + tx] = f2bf(tl[tx][e]);
  }
}

// ------------------------------------------------ pack W [K][N] -> Wt bf16 [N][K]
__global__ __launch_bounds__(256)
void pack_wt(const float* __restrict__ W, u16* __restrict__ out, int K, int N) {
  __shared__ float tl[64][65];
  int ntiles = N >> 6;
  int kt = blockIdx.x / ntiles, nt = blockIdx.x % ntiles;
  int t = threadIdx.x, tx = t & 63, ty = t >> 6;
#pragma unroll
  for (int i = 0; i < 16; ++i) {
    int kr = ty * 16 + i;
    tl[kr][tx] = W[(size_t)(kt * 64 + kr) * N + nt * 64 + tx];
  }
  __syncthreads();
#pragma unroll
  for (int i = 0; i < 16; ++i) {
    int nr = ty * 16 + i;
    out[(size_t)(nt * 64 + nr) * K + kt * 64 + tx] = f2bf(tl[tx][nr]);
  }
}

// ================================================================ 128x256 GEMM
// C[M,N] = A[M,K] * Bt[N,K]^T.  512 threads = 8 waves (2x4), wave-tile 64x64.
// 3 LDS slots (72 KB -> 2 blocks/CU), lookahead-2 staging, counted vmcnt,
// SINGLE raw barrier per K-step:
//   { vmcnt(3); s_barrier; STAGE(t+2); ds_read slot t; MFMA }
// Safety: by barrier_t every wave executed its t-1 MFMAs => its t-1 ds_reads
// completed (lgkmcnt), so STAGE(t+2) -> slot(t-1) issued after the barrier
// cannot race; slot-t readiness = own vmcnt(3) (STAGE(t) issued 2 iters ago,
// only STAGE(t+1)'s 3 loads may be younger) + barrier (all waves waited).
// LDS bank swizzle: 16B-chunk col ^= (row>>1)&3 on staging SOURCE (linear LDS
// dest, per global_load_lds rules) and on read addresses.
// NOTE (R13 post-mortem): 256^2 wave-tiles (acc[8][4]=128 regs) cannot fit
// the (512,4) register budget -> spills (R13: 2.4GB scratch writes, 740us).
// This 64x64 wave-tile at 2 blocks/CU is the proven optimum of the family.
// EPI: 1 = f32+bias; 2 = bf16+bias+GELU; 3 = QKV pack; 4 = bf16+bias.
template <int EPI>
__global__ __launch_bounds__(512, 4)
void gemm256(const u16* __restrict__ A, const u16* __restrict__ Bt,
             void* __restrict__ Cout, const float* __restrict__ bias,
             int M, int N, int K,
             u16* __restrict__ qp_out, u16* __restrict__ kp_out,
             u16* __restrict__ vt_out) {
  constexpr int BM = 128, BN = 256;
  constexpr int SLOT = (BM + BN) * 32;  // u16 per slot (12288)
  __shared__ __align__(16) u16 lds[3 * SLOT];

  const int t = threadIdx.x;
  const int lane = t & 63, w = t >> 6;
  const int li = lane & 15, lg = lane >> 4;
  const int wm = w >> 2, wn = w & 3;

  const int tiles_n = N >> 8;
  const int nwg = gridDim.x;
  const int wgid = (blockIdx.x & 7) * (nwg >> 3) + (blockIdx.x >> 3);
  const int m0 = (wgid / tiles_n) * BM;
  const int n0 = (wgid % tiles_n) << 8;

  const int srow = t >> 2;
  const int scol = (((t & 3) ^ ((t >> 3) & 3)) << 3);  // swizzled source col
  const u16* aS0 = A  + (size_t)(m0 + srow) * K + scol;
  const u16* bS0 = Bt + (size_t)(n0 + srow) * K + scol;
  const u16* bS1 = Bt + (size_t)(n0 + 128 + srow) * K + scol;
  u16* dWave = &lds[w * 512];           // wave-uniform LDS dest base

  int aOff[4], bOff[4];
#pragma unroll
  for (int i = 0; i < 4; ++i) {
    int row = wm * 64 + i * 16 + li;
    aOff[i] = row * 32 + ((lg ^ ((row >> 1) & 3)) << 3);
  }
#pragma unroll
  for (int j = 0; j < 4; ++j) {
    int row = wn * 64 + j * 16 + li;
    bOff[j] = BM * 32 + row * 32 + ((lg ^ ((row >> 1) & 3)) << 3);
  }

  f32x4 acc[4][4] = {};
  const int NT = K >> 5;

#define STAGE256(TT, SL)                                             \
  {                                                                  \
    const int kk = (TT) << 5;                                        \
    u16* db = dWave + (SL) * SLOT;                                   \
    gl_lds16(aS0 + kk, db);                                          \
    gl_lds16(bS0 + kk, db + BM * 32);                                \
    gl_lds16(bS1 + kk, db + BM * 32 + 4096);                         \
  }

  STAGE256(0, 0);
  STAGE256(1, 1);

  int so = 0;
  for (int tt = 0; tt < NT; ++tt) {
    if (tt + 1 < NT) asm volatile("s_waitcnt vmcnt(3)" ::: "memory");
    else             asm volatile("s_waitcnt vmcnt(0)" ::: "memory");
    __builtin_amdgcn_s_barrier();          // single barrier per K-step
    __builtin_amdgcn_sched_barrier(0);     // nothing moves across

    int s2 = so + 2; if (s2 >= 3) s2 -= 3;
    if (tt + 2 < NT) STAGE256(tt + 2, s2); // writes slot read at t-1 (safe)

    const u16* sb = &lds[so * SLOT];
    bf16x8 af[4], bfr[4];
#pragma unroll
    for (int i = 0; i < 4; ++i) af[i] = *(const bf16x8*)&sb[aOff[i]];
#pragma unroll
    for (int j = 0; j < 4; ++j) bfr[j] = *(const bf16x8*)&sb[bOff[j]];

    __builtin_amdgcn_s_setprio(1);
#pragma unroll
    for (int i = 0; i < 4; ++i)
#pragma unroll
      for (int j = 0; j < 4; ++j)
        acc[i][j] = mfma16(af[i], bfr[j], acc[i][j]);
    __builtin_amdgcn_s_setprio(0);

    so = (so + 1 == 3) ? 0 : so + 1;
  }
#undef STAGE256

  if constexpr (EPI == 3) {
    const int which = n0 >> 10;                 // block-uniform: 0=q 1=k 2=v
    const int colb = (n0 & 1023) + wn * 64 + li;
#pragma unroll
    for (int i = 0; i < 4; ++i) {
      const int row0 = m0 + wm * 64 + i * 16 + lg * 4;
      const int bb = row0 >> 10;
      const int s0r = row0 & 1023;
#pragma unroll
      for (int j = 0; j < 4; ++j) {
        const int c = colb + j * 16;
        const int hh = c >> 6, e = c & 63;
        const size_t hb = ((size_t)(bb * 16 + hh)) << 16;   // bh * 1024*64
        if (which == 2) {
          u16x4 pk;
#pragma unroll
          for (int r = 0; r < 4; ++r) pk[r] = f2bf(acc[i][j][r]);
          const int s_sw = (s0r & ~12) | ((s0r & 4) << 1) | ((s0r & 8) >> 1);
          *(u16x4*)(vt_out + hb + ((size_t)e << 10) + s_sw) = pk;
        } else {
          u16* dst = (which == 0) ? qp_out : kp_out;
#pragma unroll
          for (int r = 0; r < 4; ++r)
            dst[hb + (size_t)(s0r + r) * 64 + e] = f2bf(acc[i][j][r]);
        }
      }
    }
    return;
  }

  const int colBase = n0 + wn * 64 + li;
#pragma unroll
  for (int i = 0; i < 4; ++i) {
#pragma unroll
    for (int j = 0; j < 4; ++j) {
      int col = colBase + j * 16;
      float bv = bias[col];
#pragma unroll
      for (int r = 0; r < 4; ++r) {
        int row = m0 + wm * 64 + i * 16 + lg * 4 + r;
        float v = acc[i][j][r] + bv;
        if (EPI == 2) v = 0.5f * v * (1.0f + erff(v * 0.70710678118654752f));
        if (EPI == 1) ((float*)Cout)[(size_t)row * N + col] = v;
        else          ((u16*)Cout)[(size_t)row * N + col] = f2bf(v);
      }
    }
  }
}

// ------------------------------------------------ flash attention, 32x32 swapped-QK^T
// qp/kp: [BH][S][64] bf16; vt: [BH][64][S] bf16 (s-cols bit2<->3 swizzled)
// K/V staged in LDS, double-buffered, slot-major [8 d-slots][64 rows]x16B.
__global__ __launch_bounds__(256, 2)
void attn32(const u16* __restrict__ qp, const u16* __restrict__ kp,
            const u16* __restrict__ vt, u16* __restrict__ ctx) {
  __shared__ __align__(16) u16 lds[2][2][4096];   // [buf][K=0/V=1][8KB]
  const int t = threadIdx.x, l = t & 63, w = t >> 6;
  const int l31 = l & 31, hi = l >> 5;
  const int bid = blockIdx.x;
  const int idx = bid >> 3;                 // 0..127
  const int bh = (bid & 7) * 16 + (idx >> 3);
  const int qt = idx & 7;
  const int b = bh >> 4, h = bh & 15;
  const int qg = qt * 128 + w * 32;
  const size_t base = (size_t)bh << 16;
  const float SC = 0.18033688011112042f;    // 0.125 * log2(e)

  const u16* qrow = qp + base + (size_t)(qg + l31) * 64 + 8 * hi;
  bf16x8 qb[4];
#pragma unroll
  for (int f = 0; f < 4; ++f) qb[f] = *(const bf16x8*)(qrow + f * 16);

  const u16* kbh = kp + base;
  const u16* vbh = vt + base;
  const int sl0 = w, sl1 = 4 + w;

#define STAGE_KV(KB, BUF)                                                        \
  {                                                                              \
    u16* KT = &lds[BUF][0][0];                                                   \
    u16* VT = &lds[BUF][1][0];                                                   \
    const u16* ks = kbh + (size_t)(KB) * 4096;                                   \
    const u16* vs = vbh + (KB) * 64;                                             \
    gl_lds16(ks + (size_t)l * 64 + sl0 * 8,   KT + sl0 * 512);                   \
    gl_lds16(ks + (size_t)l * 64 + sl1 * 8,   KT + sl1 * 512);                   \
    gl_lds16(vs + (size_t)l * 1024 + sl0 * 8, VT + sl0 * 512);                   \
    gl_lds16(vs + (size_t)l * 1024 + sl1 * 8, VT + sl1 * 512);                   \
  }

  f32x16 o0 = {}, o1 = {};
  float m_run = -1e30f, l_run = 0.0f;

  STAGE_KV(0, 0);
  __syncthreads();

  int buf = 0;
  for (int kb = 0; kb < 16; ++kb) {
    if (kb < 15) STAGE_KV(kb + 1, buf ^ 1);

    const u16* KT = &lds[buf][0][0];
    const u16* VT = &lds[buf][1][0];

    bf16x8 ka[8];
#pragma unroll
    for (int f = 0; f < 4; ++f) {
      const int s = (2 * f + hi) * 512 + l31 * 8;
      ka[f]     = *(const bf16x8*)&KT[s];
      ka[4 + f] = *(const bf16x8*)&KT[s + 256];
    }

    __builtin_amdgcn_s_setprio(1);
    f32x16 s0 = {}, s1 = {};
#pragma unroll
    for (int f = 0; f < 4; ++f) s0 = mfma32(ka[f], qb[f], s0);
#pragma unroll
    for (int f = 0; f < 4; ++f) s1 = mfma32(ka[4 + f], qb[f], s1);
    __builtin_amdgcn_s_setprio(0);

    bf16x8 va[8];
#pragma unroll
    for (int c = 0; c < 4; ++c) {
      const int s = (2 * c + hi) * 512 + l31 * 8;
      va[c]     = *(const bf16x8*)&VT[s];
      va[4 + c] = *(const bf16x8*)&VT[s + 256];
    }

    s0 *= SC; s1 *= SC;

    float mx = fmaxf(vmax16(s0), vmax16(s1));
    mx = fmaxf(mx, __shfl_xor(mx, 32));

    float mn = fmaxf(m_run, mx);
    float al = exp2_fast(m_run - mn);
    m_run = mn;
    l_run *= al; o0 *= al; o1 *= al;

#pragma unroll
    for (int i = 0; i < 16; ++i) s0[i] = exp2_fast(s0[i] - m_run);
#pragma unroll
    for (int i = 0; i < 16; ++i) s1[i] = exp2_fast(s1[i] - m_run);

    float sm = vsum16(s0) + vsum16(s1);
    sm += __shfl_xor(sm, 32);
    l_run += sm;

    bf16x8 pb[4];
    pack_direct(s0, &pb[0]);
    pack_direct(s1, &pb[2]);

    __builtin_amdgcn_s_setprio(1);
    o0 = mfma32(va[0], pb[0], o0);
    o0 = mfma32(va[1], pb[1], o0);
    o0 = mfma32(va[2], pb[2], o0);
    o0 = mfma32(va[3], pb[3], o0);
    o1 = mfma32(va[4], pb[0], o1);
    o1 = mfma32(va[5], pb[1], o1);
    o1 = mfma32(va[6], pb[2], o1);
    o1 = mfma32(va[7], pb[3], o1);
    __builtin_amdgcn_s_setprio(0);

    __syncthreads();
    buf ^= 1;
  }
#undef STAGE_KV

  float inv = 1.0f / l_run;
  o0 *= inv; o1 *= inv;
  u16* crow = ctx + (size_t)(b * 1024 + qg + l31) * 1024 + h * 64 + 4 * hi;
#pragma unroll
  for (int g = 0; g < 4; ++g) {
    u16x4 p0, p1;
#pragma unroll
    for (int j = 0; j < 4; ++j) { p0[j] = f2bf(o0[g * 4 + j]); p1[j] = f2bf(o1[g * 4 + j]); }
    *(u16x4*)(crow + g * 8) = p0;
    *(u16x4*)(crow + 32 + g * 8) = p1;
  }
}

// ------------------------------------------------ LayerNorm (residual fused)
// MODE 0: in1 f32 (x), in2 bf16 (attn) -> out bf16   (h = LN(x+attn))
// MODE 1: in1 bf16 (h), in2 bf16 (ff2) -> out f32    (out = LN(h+ff2))
template <int MODE>
__global__ __launch_bounds__(256)
void ln_kernel(const void* __restrict__ in1v, const u16* __restrict__ in2,
               const float* __restrict__ g, const float* __restrict__ bt,
               void* __restrict__ outv) {
  __shared__ float red[4];
  const int row = blockIdx.x;
  const int t = threadIdx.x;
  const int c = t * 4;
  const size_t base = (size_t)row * 1024 + c;

  float a0, a1, a2, a3;
  {
    u16x4 yb = *(const u16x4*)(in2 + base);
    float y0 = bf2f(yb[0]), y1 = bf2f(yb[1]), y2 = bf2f(yb[2]), y3 = bf2f(yb[3]);
    if (MODE == 0) {
      const float4 x = *(const float4*)((const float*)in1v + base);
      a0 = x.x + y0; a1 = x.y + y1; a2 = x.z + y2; a3 = x.w + y3;
    } else {
      u16x4 xb = *(const u16x4*)((const u16*)in1v + base);
      a0 = bf2f(xb[0]) + y0; a1 = bf2f(xb[1]) + y1;
      a2 = bf2f(xb[2]) + y2; a3 = bf2f(xb[3]) + y3;
    }
  }
  float sum = waveRedSum(a0 + a1 + a2 + a3);
  if ((t & 63) == 0) red[t >> 6] = sum;
  __syncthreads();
  float mean = (red[0] + red[1] + red[2] + red[3]) * (1.0f / 1024.0f);
  __syncthreads();
  float d0 = a0 - mean, d1 = a1 - mean, d2 = a2 - mean, d3 = a3 - mean;
  float sq = waveRedSum(d0 * d0 + d1 * d1 + d2 * d2 + d3 * d3);
  if ((t & 63) == 0) red[t >> 6] = sq;
  __syncthreads();
  float var = (red[0] + red[1] + red[2] + red[3]) * (1.0f / 1023.0f);
  float inv = rsqrtf(var + 1e-5f);
  const float4 gv = *(const float4*)(g + c);
  const float4 bv = *(const float4*)(bt + c);
  float o0 = d0 * inv * gv.x + bv.x;
  float o1 = d1 * inv * gv.y + bv.y;
  float o2 = d2 * inv * gv.z + bv.z;
  float o3 = d3 * inv * gv.w + bv.w;
  if (MODE == 0) {
    u16x4 ob; ob[0] = f2bf(o0); ob[1] = f2bf(o1); ob[2] = f2bf(o2); ob[3] = f2bf(o3);
    *(u16x4*)((u16*)outv + base) = ob;
  } else {
    float4 of; of.x = o0; of.y = o1; of.z = o2; of.w = o3;
    *(float4*)((float*)outv + base) = of;
  }
}

// ================================================================ launcher
extern "C" void kernel_launch(void* const* d_in, const int* in_sizes, int n_in,
                              void* d_out, int out_size, void* d_ws, size_t ws_size,
                              hipStream_t stream) {
  const float* x  = (const float*)d_in[0];
  const float* Wq = (const float*)d_in[1];
  const float* Wk = (const float*)d_in[2];
  const float* Wv = (const float*)d_in[3];
  const float* Wo = (const float*)d_in[4];
  const float* bo = (const float*)d_in[5];
  const float* g1 = (const float*)d_in[6];
  const float* b1 = (const float*)d_in[7];
  const float* W1 = (const float*)d_in[8];
  const float* c1 = (const float*)d_in[9];
  const float* W2 = (const float*)d_in[10];
  const float* c2 = (const float*)d_in[11];
  const float* g2 = (const float*)d_in[12];
  const float* b2 = (const float*)d_in[13];
  float* out = (float*)d_out;

  // workspace layout (bytes)
  char* ws = (char*)d_ws;
  u16* xb     = (u16*)(ws + 0);           // 16,777,216  (reused as h_b later)
  u16* wqkv_b = (u16*)(ws + 16777216);    //  6,291,456
  u16* wo_b   = (u16*)(ws + 23068672);    //  2,097,152
  u16* w1_b   = (u16*)(ws + 25165824);    //  8,388,608
  u16* w2_b   = (u16*)(ws + 33554432);    //  8,388,608
  char* R1 = ws + 41943040;               // 100,663,296 region, aliased over time
  u16*  qpb  = (u16*)(R1);                 // 16,777,216  live: qkv->attn
  u16*  kpb  = (u16*)(R1 + 16777216);      // 16,777,216  live: qkv->attn
  u16*  vtb  = (u16*)(R1 + 33554432);      // 16,777,216  live: qkv->attn
  u16*  ctx  = (u16*)(R1 + 50331648);      // 16,777,216  live: attn->Wo
  u16*  attn = (u16*)(R1 + 67108864);      // 16,777,216  live: Wo->ln1 (bf16)
  u16*  ff1  = (u16*)(R1);                 // 67,108,864  live: FFN1->FFN2 (aliases qp/kp/vt/ctx)
  u16*  ff2  = (u16*)(R1 + 83886080);      // 16,777,216  live: FFN2->ln2 (bf16)
  u16*  h_b  = xb;                         // live: ln1->end (aliases xb)

  cvt_f32_bf16<<<4096, 256, 0, stream>>>(x, xb, 1048576);
  pack_wqkv<<<768, 256, 0, stream>>>(Wq, Wk, Wv, wqkv_b);
  pack_wt<<<256, 256, 0, stream>>>(Wo, wo_b, 1024, 1024);
  pack_wt<<<1024, 256, 0, stream>>>(W1, w1_b, 1024, 4096);
  pack_wt<<<1024, 256, 0, stream>>>(W2, w2_b, 4096, 1024);

  // QKV: [8192,3072,1024] with q/k/vt packing epilogue
  gemm256<3><<<768, 512, 0, stream>>>(xb, wqkv_b, nullptr, nullptr,
                                      8192, 3072, 1024, qpb, kpb, vtb);
  attn32<<<1024, 256, 0, stream>>>(qpb, kpb, vtb, ctx);
  // Wo: [8192,1024,1024] -> bf16 + bias
  gemm256<4><<<256, 512, 0, stream>>>(ctx, wo_b, attn, bo, 8192, 1024, 1024,
                                      nullptr, nullptr, nullptr);
  ln_kernel<0><<<8192, 256, 0, stream>>>(x, attn, g1, b1, h_b);
  // FFN1: [8192,4096,1024] -> bf16 + bias + GELU
  gemm256<2><<<1024, 512, 0, stream>>>(h_b, w1_b, ff1, c1, 8192, 4096, 1024,
                                       nullptr, nullptr, nullptr);
  // FFN2: [8192,1024,4096] -> bf16 + bias
  gemm256<4><<<256, 512, 0, stream>>>(ff1, w2_b, ff2, c2, 8192, 1024, 4096,
                                      nullptr, nullptr, nullptr);
  ln_kernel<1><<<8192, 256, 0, stream>>>(h_b, ff2, g2, b2, out);
}